// Round 15
// baseline (105.360 us; speedup 1.0000x reference)
//
#include <hip/hip_runtime.h>
#include <hip/hip_bf16.h>
#include <hip/hip_fp16.h>
#include <math.h>

#define DD 48
#define NN 512
#define TWO_D 96
#define ROWS 2048   // B*N = 4*512
#define W2P 104     // padded LDS row (f16): 52-dword stride -> 2 lanes/bank (free)
#define NW 6        // waves per block

typedef __attribute__((ext_vector_type(8))) _Float16 f16x8;
typedef __attribute__((ext_vector_type(4))) float f32x4;
typedef __attribute__((ext_vector_type(2))) float f32x2;
typedef __attribute__((ext_vector_type(4))) unsigned int u32x4;

__device__ __forceinline__ __half2 h2cast(unsigned int u) { return __builtin_bit_cast(__half2, u); }

// Packed exact-erf GELU (deg-5 poly, verified R8-R14) on f32x2.
__device__ __forceinline__ f32x2 gelu_poly2(f32x2 u) {
    f32x2 lim;  lim  = 3.5777f;
    f32x2 nlim; nlim = -3.5777f;
    const f32x2 uc = __builtin_elementwise_min(__builtin_elementwise_max(u, nlim), lim);
    const f32x2 v = uc * uc;
    f32x2 c5; c5 = -1.04448e-6f;
    f32x2 c4; c4 = 4.61896e-5f;
    f32x2 c3; c3 = -8.62284e-4f;
    f32x2 c2; c2 = 9.22138e-3f;
    f32x2 c1; c1 = -6.58353e-2f;
    f32x2 c0; c0 = 3.98855e-1f;
    f32x2 E = __builtin_elementwise_fma(v, c5, c4);
    E = __builtin_elementwise_fma(v, E, c3);
    E = __builtin_elementwise_fma(v, E, c2);
    E = __builtin_elementwise_fma(v, E, c1);
    E = __builtin_elementwise_fma(v, E, c0);
    f32x2 hlf; hlf = 0.5f;
    return u * __builtin_elementwise_fma(uc, E, hlf);
}

// Kernel 1: blocks 0..511: A[r][t] = f16(x_r @ W1[:48,t] + b1[t]);
//           Bb[r][t] = f16(x_r @ W1[48:,t]); block 512: W2T[f][k] = f16(W2[k][f])
__global__ __launch_bounds__(256) void precompute_kernel(
        const float* __restrict__ x,
        const float* __restrict__ W1,
        const float* __restrict__ b1,
        const float* __restrict__ W2,
        __half* __restrict__ Aout,
        __half* __restrict__ Bout,
        __half* __restrict__ W2T) {
    if (blockIdx.x == ROWS / 4) {
        for (int idx = threadIdx.x; idx < DD * TWO_D; idx += 256) {
            const int f = idx / TWO_D;
            const int k = idx - f * TWO_D;
            W2T[idx] = __float2half(W2[k * DD + f]);
        }
        return;
    }
    const int wave = threadIdx.x >> 6;
    const int lane = threadIdx.x & 63;
    const int row = blockIdx.x * 4 + wave;
    __shared__ float xs[4][DD];
    if (threadIdx.x < 4 * DD)
        xs[threadIdx.x / DD][threadIdx.x % DD] = x[blockIdx.x * 4 * DD + threadIdx.x];
    __syncthreads();
    for (int t = lane; t < TWO_D; t += 64) {
        float a0 = 0.f, a1 = 0.f;
#pragma unroll 8
        for (int k = 0; k < DD; ++k) {
            const float xv = xs[wave][k];
            a0 = fmaf(xv, W1[k * TWO_D + t], a0);
            a1 = fmaf(xv, W1[(DD + k) * TWO_D + t], a1);
        }
        Aout[row * TWO_D + t] = __float2half(a0 + b1[t]);
        Bout[row * TWO_D + t] = __float2half(a1);
    }
}

// Single-stream per-row loop (textual macro, constant-indexed -> registers).
// avp/pb in regs; bfrag from LDS (free 2-way); acc initialized from b2 in LDS
// (broadcast ds_read, saves 12 VGPRs); rolling clamped prefetch.
#define PROCESS_ROW_S(I_, ROW_, CSTART_, L_, O_)                                \
  { u32x4 avp[3];                                                               \
    _Pragma("unroll")                                                           \
    for (int ks = 0; ks < 3; ++ks)                                              \
      avp[ks] = *(const u32x4*)&Arow[(size_t)(ROW_) * TWO_D + ks * 32 + q8];    \
    const int nch = ((I_) + 16) >> 4;                                           \
    int c = (CSTART_);                                                          \
    if (c < nch) {                                                              \
      const __half* __restrict__ Bp = Bbase + (size_t)((c << 4) + n) * TWO_D;   \
      u32x4 pb[3];                                                              \
      _Pragma("unroll")                                                         \
      for (int ks = 0; ks < 3; ++ks)                                            \
        pb[ks] = *(const u32x4*)&Bp[ks * 32 + q8];                              \
      for (; c < nch; c += NW) {                                                \
        const __half* __restrict__ Bn =                                         \
            ((c + NW) < nch) ? Bp + (NW * 16) * TWO_D : Bp;  /* clamped */      \
        f32x4 acc[3];                                                           \
        acc[0] = *(const f32x4*)&b2s[0 * 16 + 4 * q];                           \
        acc[1] = *(const f32x4*)&b2s[1 * 16 + 4 * q];                           \
        acc[2] = *(const f32x4*)&b2s[2 * 16 + 4 * q];                           \
        _Pragma("unroll")                                                       \
        for (int ks = 0; ks < 3; ++ks) {                                        \
          const f16x8 bf0 = *(const f16x8*)&w2s[(0 * 16 + n) * W2P + ks * 32 + q8]; \
          const f16x8 bf1 = *(const f16x8*)&w2s[(1 * 16 + n) * W2P + ks * 32 + q8]; \
          const f16x8 bf2 = *(const f16x8*)&w2s[(2 * 16 + n) * W2P + ks * 32 + q8]; \
          const u32x4 aw = avp[ks];                                             \
          const u32x4 bw = pb[ks];                                              \
          pb[ks] = *(const u32x4*)&Bn[ks * 32 + q8];                            \
          const __half2 u0 = __hadd2(h2cast(aw.x), h2cast(bw.x));               \
          const __half2 u1 = __hadd2(h2cast(aw.y), h2cast(bw.y));               \
          const __half2 u2 = __hadd2(h2cast(aw.z), h2cast(bw.z));               \
          const __half2 u3 = __hadd2(h2cast(aw.w), h2cast(bw.w));               \
          f32x2 f0, f1, f2, f3;                                                 \
          { float2 t_ = __half22float2(u0); f0.x = t_.x; f0.y = t_.y; }         \
          { float2 t_ = __half22float2(u1); f1.x = t_.x; f1.y = t_.y; }         \
          { float2 t_ = __half22float2(u2); f2.x = t_.x; f2.y = t_.y; }         \
          { float2 t_ = __half22float2(u3); f3.x = t_.x; f3.y = t_.y; }         \
          const f32x2 g0 = gelu_poly2(f0);                                      \
          const f32x2 g1 = gelu_poly2(f1);                                      \
          const f32x2 g2 = gelu_poly2(f2);                                      \
          const f32x2 g3 = gelu_poly2(f3);                                      \
          union { f16x8 v; __half2 h2[4]; } hf;                                 \
          hf.h2[0] = __float22half2_rn(make_float2(g0.x, g0.y));                \
          hf.h2[1] = __float22half2_rn(make_float2(g1.x, g1.y));                \
          hf.h2[2] = __float22half2_rn(make_float2(g2.x, g2.y));                \
          hf.h2[3] = __float22half2_rn(make_float2(g3.x, g3.y));                \
          acc[0] = __builtin_amdgcn_mfma_f32_16x16x32_f16(bf0, hf.v, acc[0], 0, 0, 0); \
          acc[1] = __builtin_amdgcn_mfma_f32_16x16x32_f16(bf1, hf.v, acc[1], 0, 0, 0); \
          acc[2] = __builtin_amdgcn_mfma_f32_16x16x32_f16(bf2, hf.v, acc[2], 0, 0, 0); \
        }                                                                       \
        /* epilogue: lane holds P[f=t*16+4q+r][j=(c<<4)+n]; b2 already in acc */\
        f32x2 pv[3][2];                                                         \
        f32x2 ss2; ss2 = 0.f;                                                   \
        _Pragma("unroll")                                                       \
        for (int t = 0; t < 3; ++t) {                                           \
          pv[t][0].x = acc[t][0]; pv[t][0].y = acc[t][1];                       \
          pv[t][1].x = acc[t][2]; pv[t][1].y = acc[t][3];                       \
          ss2 = __builtin_elementwise_fma(pv[t][0], pv[t][0], ss2);             \
          ss2 = __builtin_elementwise_fma(pv[t][1], pv[t][1], ss2);             \
        }                                                                       \
        float ss = ss2.x + ss2.y;                                               \
        ss += __shfl_xor(ss, 16);                                               \
        ss += __shfl_xor(ss, 32);                                               \
        const int j = (c << 4) + n;                                             \
        const float ew = (j <= (I_))                                            \
            ? __builtin_amdgcn_exp2f(sqrtf(ss) * 1.44269504f) : 0.f;            \
        L_ += ew;                                                               \
        f32x2 ew2; ew2 = ew;                                                    \
        _Pragma("unroll")                                                       \
        for (int t = 0; t < 3; ++t) {                                           \
          O_[t][0] = __builtin_elementwise_fma(ew2, pv[t][0], O_[t][0]);        \
          O_[t][1] = __builtin_elementwise_fma(ew2, pv[t][1], O_[t][1]);        \
        }                                                                       \
        Bp = Bn;                                                                \
      }                                                                         \
    } }

// reduce over n (16 lanes) and flush one row's partials to per-wave LDS slots
#define REDUCE_FLUSH(L_, O_, SEL_)                                              \
  { _Pragma("unroll")                                                           \
    for (int d = 1; d <= 8; d <<= 1) {                                          \
      L_ += __shfl_xor(L_, d);                                                  \
      _Pragma("unroll")                                                         \
      for (int t = 0; t < 3; ++t)                                               \
        _Pragma("unroll")                                                       \
        for (int r = 0; r < 2; ++r) {                                           \
          O_[t][r].x += __shfl_xor(O_[t][r].x, d);                              \
          O_[t][r].y += __shfl_xor(O_[t][r].y, d);                              \
        }                                                                       \
    }                                                                           \
    if (n == 0) {                                                               \
      _Pragma("unroll")                                                         \
      for (int t = 0; t < 3; ++t)                                               \
        _Pragma("unroll")                                                       \
        for (int r = 0; r < 2; ++r) {                                           \
          ored[wave][SEL_][t * 16 + 4 * q + 2 * r + 0] = O_[t][r].x;            \
          ored[wave][SEL_][t * 16 + 4 * q + 2 * r + 1] = O_[t][r].y;            \
        }                                                                       \
      if (q == 0) lred[wave][SEL_] = L_;                                        \
    } }

// Kernel 2: one block per (batch, row-PAIR (p, 511-p)); 33 chunks/block uniform;
// 1024 blocks x 6 WAVES (384 thr) -> 24 waves/CU target (TLP 4->6 per SIMD).
// Single-stream f16 engine, LDS W2T + LDS b2 acc-init to keep VGPR <= 85.
__global__ __launch_bounds__(384) void pair_softmax_kernel(
        const __half* __restrict__ Arow,
        const __half* __restrict__ Brow,
        const __half* __restrict__ W2T,
        const float* __restrict__ b2,
        float* __restrict__ out) {
    const int batch = blockIdx.x >> 8;        // 0..3
    const int pr = blockIdx.x & 255;          // 0..255
    const int iH = (NN - 1) - pr;             // 256..511
    const int iL = pr;                        // 0..255
    const int cH = (iH >> 4) + 1;             // 17..32; cH + cL = 33
    const int rowH = batch * NN + iH;
    const int rowL = batch * NN + iL;
    const __half* __restrict__ Bbase = Brow + (size_t)batch * NN * TWO_D;

    const int tid = threadIdx.x;
    const int wave = tid >> 6;                // 0..5
    const int lane = tid & 63;
    const int n = lane & 15;   // j-local (C/D col); also W2T A-frag row f-local
    const int q = lane >> 4;   // quad
    const int q8 = q * 8;

    __shared__ __align__(16) __half w2s[DD * W2P];   // padded W2T, ~10 KB
    __shared__ __align__(16) float b2s[DD];
    __shared__ float lred[NW][2];
    __shared__ float ored[NW][2][DD];

    for (int idx = tid; idx < DD * TWO_D; idx += 384) {
        const int f = idx / TWO_D;
        const int k = idx - f * TWO_D;
        w2s[f * W2P + k] = W2T[idx];
    }
    if (tid < DD) b2s[tid] = b2[tid];
    __syncthreads();

    // Light row's starting chunk: global idx = cH + c ≡ wave (mod 6)
    int cstartL = (wave - cH) % NW;
    if (cstartL < 0) cstartL += NW;

    float lH = 0.f;
    f32x2 oH[3][2];
#pragma unroll
    for (int t = 0; t < 3; ++t)
#pragma unroll
        for (int r = 0; r < 2; ++r) oH[t][r] = 0.f;
    PROCESS_ROW_S(iH, rowH, wave, lH, oH);
    REDUCE_FLUSH(lH, oH, 0);

    float lL = 0.f;
    f32x2 oL[3][2];
#pragma unroll
    for (int t = 0; t < 3; ++t)
#pragma unroll
        for (int r = 0; r < 2; ++r) oL[t][r] = 0.f;
    PROCESS_ROW_S(iL, rowL, cstartL, lL, oL);
    REDUCE_FLUSH(lL, oL, 1);

    __syncthreads();
    if (tid < 2 * DD) {
        const int sel = tid / DD;
        const int f = tid - sel * DD;
        float L = 0.f, O = 0.f;
#pragma unroll
        for (int wv = 0; wv < NW; ++wv) {
            L += lred[wv][sel];
            O += ored[wv][sel][f];
        }
        const int row = sel ? rowL : rowH;
        out[row * DD + f] = O / L;
    }
}

extern "C" void kernel_launch(void* const* d_in, const int* in_sizes, int n_in,
                              void* d_out, int out_size, void* d_ws, size_t ws_size,
                              hipStream_t stream) {
    const float* x  = (const float*)d_in[0];
    const float* W1 = (const float*)d_in[1];
    const float* b1 = (const float*)d_in[2];
    const float* W2 = (const float*)d_in[3];
    const float* b2 = (const float*)d_in[4];
    float* outp = (float*)d_out;

    __half* A   = (__half*)d_ws;            // 2048*96 f16
    __half* Bb  = A + ROWS * TWO_D;         // 2048*96 f16
    __half* W2T = Bb + ROWS * TWO_D;        // 48*96 f16

    precompute_kernel<<<ROWS / 4 + 1, 256, 0, stream>>>(x, W1, b1, W2, A, Bb, W2T);
    pair_softmax_kernel<<<1024, 384, 0, stream>>>(A, Bb, W2T, b2, outp);
}

// Round 16
// 91.270 us; speedup vs baseline: 1.1544x; 1.1544x over previous
//
#include <hip/hip_runtime.h>
#include <hip/hip_bf16.h>
#include <hip/hip_fp16.h>
#include <math.h>

#define DD 48
#define NN 512
#define TWO_D 96
#define ROWS 2048   // B*N = 4*512

typedef __attribute__((ext_vector_type(8))) _Float16 f16x8;
typedef __attribute__((ext_vector_type(4))) float f32x4;
typedef __attribute__((ext_vector_type(2))) float f32x2;
typedef __attribute__((ext_vector_type(4))) unsigned int u32x4;

__device__ __forceinline__ __half2 h2cast(unsigned int u) { return __builtin_bit_cast(__half2, u); }

// Packed exact-erf GELU (deg-5 poly, verified R8-R15) on f32x2.
__device__ __forceinline__ f32x2 gelu_poly2(f32x2 u) {
    f32x2 lim;  lim  = 3.5777f;
    f32x2 nlim; nlim = -3.5777f;
    const f32x2 uc = __builtin_elementwise_min(__builtin_elementwise_max(u, nlim), lim);
    const f32x2 v = uc * uc;
    f32x2 c5; c5 = -1.04448e-6f;
    f32x2 c4; c4 = 4.61896e-5f;
    f32x2 c3; c3 = -8.62284e-4f;
    f32x2 c2; c2 = 9.22138e-3f;
    f32x2 c1; c1 = -6.58353e-2f;
    f32x2 c0; c0 = 3.98855e-1f;
    f32x2 E = __builtin_elementwise_fma(v, c5, c4);
    E = __builtin_elementwise_fma(v, E, c3);
    E = __builtin_elementwise_fma(v, E, c2);
    E = __builtin_elementwise_fma(v, E, c1);
    E = __builtin_elementwise_fma(v, E, c0);
    f32x2 hlf; hlf = 0.5f;
    return u * __builtin_elementwise_fma(uc, E, hlf);
}

// Kernel 1: blocks 0..511: A[r][t] = f16(x_r @ W1[:48,t] + b1[t]);
//           Bb[r][t] = f16(x_r @ W1[48:,t]); block 512: W2T[f][k] = f16(W2[k][f])
__global__ __launch_bounds__(256) void precompute_kernel(
        const float* __restrict__ x,
        const float* __restrict__ W1,
        const float* __restrict__ b1,
        const float* __restrict__ W2,
        __half* __restrict__ Aout,
        __half* __restrict__ Bout,
        __half* __restrict__ W2T) {
    if (blockIdx.x == ROWS / 4) {
        for (int idx = threadIdx.x; idx < DD * TWO_D; idx += 256) {
            const int f = idx / TWO_D;
            const int k = idx - f * TWO_D;
            W2T[idx] = __float2half(W2[k * DD + f]);
        }
        return;
    }
    const int wave = threadIdx.x >> 6;
    const int lane = threadIdx.x & 63;
    const int row = blockIdx.x * 4 + wave;
    __shared__ float xs[4][DD];
    if (threadIdx.x < 4 * DD)
        xs[threadIdx.x / DD][threadIdx.x % DD] = x[blockIdx.x * 4 * DD + threadIdx.x];
    __syncthreads();
    for (int t = lane; t < TWO_D; t += 64) {
        float a0 = 0.f, a1 = 0.f;
#pragma unroll 8
        for (int k = 0; k < DD; ++k) {
            const float xv = xs[wave][k];
            a0 = fmaf(xv, W1[k * TWO_D + t], a0);
            a1 = fmaf(xv, W1[(DD + k) * TWO_D + t], a1);
        }
        Aout[row * TWO_D + t] = __float2half(a0 + b1[t]);
        Bout[row * TWO_D + t] = __float2half(a1);
    }
}

// one stream's hadd2+gelu+pack+3 MFMA for one ks step; prefetch into PB_
#define STREAM_KS(PB_, ACC_, PF_, NPTR_, KS_)                                   \
  { const u32x4 aw = avp[KS_];                                                  \
    const u32x4 bw = PB_[KS_];                                                  \
    if (PF_) PB_[KS_] = *(const u32x4*)&(NPTR_)[(KS_) * 32 + q8];               \
    const __half2 u0 = __hadd2(h2cast(aw.x), h2cast(bw.x));                     \
    const __half2 u1 = __hadd2(h2cast(aw.y), h2cast(bw.y));                     \
    const __half2 u2 = __hadd2(h2cast(aw.z), h2cast(bw.z));                     \
    const __half2 u3 = __hadd2(h2cast(aw.w), h2cast(bw.w));                     \
    f32x2 f0, f1, f2, f3;                                                       \
    { float2 t_ = __half22float2(u0); f0.x = t_.x; f0.y = t_.y; }               \
    { float2 t_ = __half22float2(u1); f1.x = t_.x; f1.y = t_.y; }               \
    { float2 t_ = __half22float2(u2); f2.x = t_.x; f2.y = t_.y; }               \
    { float2 t_ = __half22float2(u3); f3.x = t_.x; f3.y = t_.y; }               \
    const f32x2 g0 = gelu_poly2(f0);                                            \
    const f32x2 g1 = gelu_poly2(f1);                                            \
    const f32x2 g2 = gelu_poly2(f2);                                            \
    const f32x2 g3 = gelu_poly2(f3);                                            \
    union { f16x8 v; __half2 h2[4]; } hf;                                       \
    hf.h2[0] = __float22half2_rn(make_float2(g0.x, g0.y));                      \
    hf.h2[1] = __float22half2_rn(make_float2(g1.x, g1.y));                      \
    hf.h2[2] = __float22half2_rn(make_float2(g2.x, g2.y));                      \
    hf.h2[3] = __float22half2_rn(make_float2(g3.x, g3.y));                      \
    ACC_[0] = __builtin_amdgcn_mfma_f32_16x16x32_f16(bfrag[0][KS_], hf.v, ACC_[0], 0, 0, 0); \
    ACC_[1] = __builtin_amdgcn_mfma_f32_16x16x32_f16(bfrag[1][KS_], hf.v, ACC_[1], 0, 0, 0); \
    ACC_[2] = __builtin_amdgcn_mfma_f32_16x16x32_f16(bfrag[2][KS_], hf.v, ACC_[2], 0, 0, 0); \
  }

// epilogue: lane holds P[f=t*16+4q+r][j=J0_+n]; b2 already in ACC
#define CHUNK_EPI(J0_, I_, ACC_, L_, O_)                                        \
  { f32x2 pv[3][2];                                                             \
    f32x2 ss2; ss2 = 0.f;                                                       \
    _Pragma("unroll")                                                           \
    for (int t = 0; t < 3; ++t) {                                               \
      pv[t][0].x = ACC_[t][0]; pv[t][0].y = ACC_[t][1];                         \
      pv[t][1].x = ACC_[t][2]; pv[t][1].y = ACC_[t][3];                         \
      ss2 = __builtin_elementwise_fma(pv[t][0], pv[t][0], ss2);                 \
      ss2 = __builtin_elementwise_fma(pv[t][1], pv[t][1], ss2);                 \
    }                                                                           \
    float ss = ss2.x + ss2.y;                                                   \
    ss += __shfl_xor(ss, 16);                                                   \
    ss += __shfl_xor(ss, 32);                                                   \
    const int j = (J0_) + n;                                                    \
    const float ew = (j <= (I_))                                                \
        ? __builtin_amdgcn_exp2f(sqrtf(ss) * 1.44269504f) : 0.f;                \
    L_ += ew;                                                                   \
    f32x2 ew2; ew2 = ew;                                                        \
    _Pragma("unroll")                                                           \
    for (int t = 0; t < 3; ++t) {                                               \
      O_[t][0] = __builtin_elementwise_fma(ew2, pv[t][0], O_[t][0]);            \
      O_[t][1] = __builtin_elementwise_fma(ew2, pv[t][1], O_[t][1]);            \
    } }

// one row, dual chunk streams (c, c+4) stepping 8 (R11-proven shape)
#define PROCESS_ROW_DUAL(I_, ROW_, CSTART_, L_, O_)                             \
  { u32x4 avp[3];                                                               \
    _Pragma("unroll")                                                           \
    for (int ks = 0; ks < 3; ++ks)                                              \
      avp[ks] = *(const u32x4*)&Arow[(size_t)(ROW_) * TWO_D + ks * 32 + q8];    \
    const int nch = ((I_) + 16) >> 4;                                           \
    int c = (CSTART_);                                                          \
    const __half* __restrict__ Bp = Bbase + (size_t)((c << 4) + n) * TWO_D;     \
    u32x4 pbA[3], pbB[3];                                                       \
    if (c < nch) {                                                              \
      _Pragma("unroll")                                                         \
      for (int ks = 0; ks < 3; ++ks) pbA[ks] = *(const u32x4*)&Bp[ks * 32 + q8];\
    }                                                                           \
    if (c + 4 < nch) {                                                          \
      const __half* __restrict__ B2_ = Bp + 64 * TWO_D;                         \
      _Pragma("unroll")                                                         \
      for (int ks = 0; ks < 3; ++ks) pbB[ks] = *(const u32x4*)&B2_[ks * 32 + q8];\
    }                                                                           \
    for (; c + 4 < nch; c += 8) {                                               \
      const bool pfA = (c + 8) < nch;                                           \
      const bool pfB = (c + 12) < nch;                                          \
      const __half* __restrict__ BpA = Bp + 128 * TWO_D;                        \
      const __half* __restrict__ BpB = Bp + 192 * TWO_D;                        \
      f32x4 accA[3], accB[3];                                                   \
      accA[0] = b2q[0]; accA[1] = b2q[1]; accA[2] = b2q[2];                     \
      accB[0] = b2q[0]; accB[1] = b2q[1]; accB[2] = b2q[2];                     \
      _Pragma("unroll")                                                         \
      for (int ksi = 0; ksi < 3; ++ksi) {                                       \
        STREAM_KS(pbA, accA, pfA, BpA, ksi);                                    \
        STREAM_KS(pbB, accB, pfB, BpB, ksi);                                    \
      }                                                                         \
      CHUNK_EPI((c << 4), I_, accA, L_, O_);                                    \
      CHUNK_EPI(((c + 4) << 4), I_, accB, L_, O_);                              \
      Bp = BpA;                                                                 \
    }                                                                           \
    if (c < nch) {                                                              \
      f32x4 accA[3];                                                            \
      accA[0] = b2q[0]; accA[1] = b2q[1]; accA[2] = b2q[2];                     \
      _Pragma("unroll")                                                         \
      for (int ksi = 0; ksi < 3; ++ksi) { STREAM_KS(pbA, accA, false, Bp, ksi); } \
      CHUNK_EPI((c << 4), I_, accA, L_, O_);                                    \
    } }

// reduce over n (16 lanes) and flush one row's partials to per-wave LDS slots
#define REDUCE_FLUSH(L_, O_, SEL_)                                              \
  { _Pragma("unroll")                                                           \
    for (int d = 1; d <= 8; d <<= 1) {                                          \
      L_ += __shfl_xor(L_, d);                                                  \
      _Pragma("unroll")                                                         \
      for (int t = 0; t < 3; ++t)                                               \
        _Pragma("unroll")                                                       \
        for (int r = 0; r < 2; ++r) {                                           \
          O_[t][r].x += __shfl_xor(O_[t][r].x, d);                              \
          O_[t][r].y += __shfl_xor(O_[t][r].y, d);                              \
        }                                                                       \
    }                                                                           \
    if (n == 0) {                                                               \
      _Pragma("unroll")                                                         \
      for (int t = 0; t < 3; ++t)                                               \
        _Pragma("unroll")                                                       \
        for (int r = 0; r < 2; ++r) {                                           \
          ored[wave][SEL_][t * 16 + 4 * q + 2 * r + 0] = O_[t][r].x;            \
          ored[wave][SEL_][t * 16 + 4 * q + 2 * r + 1] = O_[t][r].y;            \
        }                                                                       \
      if (q == 0) lred[wave][SEL_] = L_;                                        \
    } }

// Kernel 2: 1024 uniform pair-blocks x 4 waves (R11 champion skeleton), f16 data
// path, ALL hot-loop operands register-resident (bfrag 36 + b2q 12 VGPRs; no LDS
// traffic in the loop except the 2 epilogue swizzles -> minimal LDS-pipe load).
__global__ __launch_bounds__(256) void pair_softmax_kernel(
        const __half* __restrict__ Arow,
        const __half* __restrict__ Brow,
        const __half* __restrict__ W2T,
        const float* __restrict__ b2,
        float* __restrict__ out) {
    const int batch = blockIdx.x >> 8;        // 0..3
    const int pr = blockIdx.x & 255;          // 0..255
    const int iH = (NN - 1) - pr;             // 256..511
    const int iL = pr;                        // 0..255
    const int cH = (iH >> 4) + 1;             // 17..32; cH + cL = 33
    const int rowH = batch * NN + iH;
    const int rowL = batch * NN + iL;
    const __half* __restrict__ Bbase = Brow + (size_t)batch * NN * TWO_D;

    const int tid = threadIdx.x;
    const int wave = tid >> 6;                // 0..3
    const int lane = tid & 63;
    const int n = lane & 15;   // j-local (C/D col); also W2T A-frag row f-local
    const int q = lane >> 4;   // quad
    const int q8 = q * 8;

    __shared__ float lred[4][2];
    __shared__ float ored[4][2][DD];

    // W2T fragments (A-operand) in registers: lane holds W2T[f=t*16+n][ks*32+q8+0..7]
    f16x8 bfrag[3][3];
#pragma unroll
    for (int t = 0; t < 3; ++t)
#pragma unroll
        for (int ks = 0; ks < 3; ++ks)
            bfrag[t][ks] = *(const f16x8*)&W2T[(t * 16 + n) * TWO_D + ks * 32 + q8];
    // b2 quad for this lane's C/D rows: f = t*16 + 4q + r (folded into acc init)
    f32x4 b2q[3];
#pragma unroll
    for (int t = 0; t < 3; ++t)
        b2q[t] = *(const f32x4*)&b2[t * 16 + 4 * q];

    // Light row's starting chunk: global idx = cH + c ≡ wave (mod 4)
    const int cstartL = (wave + 128 - cH) & 3;

    float lH = 0.f;
    f32x2 oH[3][2];
#pragma unroll
    for (int t = 0; t < 3; ++t)
#pragma unroll
        for (int r = 0; r < 2; ++r) oH[t][r] = 0.f;
    PROCESS_ROW_DUAL(iH, rowH, wave, lH, oH);
    REDUCE_FLUSH(lH, oH, 0);

    float lL = 0.f;
    f32x2 oL[3][2];
#pragma unroll
    for (int t = 0; t < 3; ++t)
#pragma unroll
        for (int r = 0; r < 2; ++r) oL[t][r] = 0.f;
    PROCESS_ROW_DUAL(iL, rowL, cstartL, lL, oL);
    REDUCE_FLUSH(lL, oL, 1);

    __syncthreads();
    if (tid < 2 * DD) {
        const int sel = tid / DD;
        const int f = tid - sel * DD;
        float L = 0.f, O = 0.f;
#pragma unroll
        for (int wv = 0; wv < 4; ++wv) {
            L += lred[wv][sel];
            O += ored[wv][sel][f];
        }
        const int row = sel ? rowL : rowH;
        out[row * DD + f] = O / L;
    }
}

extern "C" void kernel_launch(void* const* d_in, const int* in_sizes, int n_in,
                              void* d_out, int out_size, void* d_ws, size_t ws_size,
                              hipStream_t stream) {
    const float* x  = (const float*)d_in[0];
    const float* W1 = (const float*)d_in[1];
    const float* b1 = (const float*)d_in[2];
    const float* W2 = (const float*)d_in[3];
    const float* b2 = (const float*)d_in[4];
    float* outp = (float*)d_out;

    __half* A   = (__half*)d_ws;            // 2048*96 f16
    __half* Bb  = A + ROWS * TWO_D;         // 2048*96 f16
    __half* W2T = Bb + ROWS * TWO_D;        // 48*96 f16

    precompute_kernel<<<ROWS / 4 + 1, 256, 0, stream>>>(x, W1, b1, W2, A, Bb, W2T);
    pair_softmax_kernel<<<1024, 256, 0, stream>>>(A, Bb, W2T, b2, outp);
}

// Round 17
// 89.685 us; speedup vs baseline: 1.1748x; 1.0177x over previous
//
#include <hip/hip_runtime.h>
#include <hip/hip_bf16.h>
#include <hip/hip_fp16.h>
#include <math.h>

#define DD 48
#define NN 512
#define TWO_D 96
#define ROWS 2048   // B*N = 4*512

typedef __attribute__((ext_vector_type(8))) _Float16 f16x8;
typedef __attribute__((ext_vector_type(4))) float f32x4;
typedef __attribute__((ext_vector_type(2))) float f32x2;
typedef __attribute__((ext_vector_type(4))) unsigned int u32x4;

__device__ __forceinline__ __half2 h2cast(unsigned int u) { return __builtin_bit_cast(__half2, u); }

// Packed exact-erf GELU (deg-5 poly, verified R8-R16) on f32x2.
__device__ __forceinline__ f32x2 gelu_poly2(f32x2 u) {
    f32x2 lim;  lim  = 3.5777f;
    f32x2 nlim; nlim = -3.5777f;
    const f32x2 uc = __builtin_elementwise_min(__builtin_elementwise_max(u, nlim), lim);
    const f32x2 v = uc * uc;
    f32x2 c5; c5 = -1.04448e-6f;
    f32x2 c4; c4 = 4.61896e-5f;
    f32x2 c3; c3 = -8.62284e-4f;
    f32x2 c2; c2 = 9.22138e-3f;
    f32x2 c1; c1 = -6.58353e-2f;
    f32x2 c0; c0 = 3.98855e-1f;
    f32x2 E = __builtin_elementwise_fma(v, c5, c4);
    E = __builtin_elementwise_fma(v, E, c3);
    E = __builtin_elementwise_fma(v, E, c2);
    E = __builtin_elementwise_fma(v, E, c1);
    E = __builtin_elementwise_fma(v, E, c0);
    f32x2 hlf; hlf = 0.5f;
    return u * __builtin_elementwise_fma(uc, E, hlf);
}

// Kernel 1: blocks 0..511: A[r][t] = f16(x_r @ W1[:48,t] + b1[t]);
//           Bb[r][t] = f16(x_r @ W1[48:,t]); block 512: W2T[f][k] = f16(W2[k][f])
__global__ __launch_bounds__(256) void precompute_kernel(
        const float* __restrict__ x,
        const float* __restrict__ W1,
        const float* __restrict__ b1,
        const float* __restrict__ W2,
        __half* __restrict__ Aout,
        __half* __restrict__ Bout,
        __half* __restrict__ W2T) {
    if (blockIdx.x == ROWS / 4) {
        for (int idx = threadIdx.x; idx < DD * TWO_D; idx += 256) {
            const int f = idx / TWO_D;
            const int k = idx - f * TWO_D;
            W2T[idx] = __float2half(W2[k * DD + f]);
        }
        return;
    }
    const int wave = threadIdx.x >> 6;
    const int lane = threadIdx.x & 63;
    const int row = blockIdx.x * 4 + wave;
    __shared__ float xs[4][DD];
    if (threadIdx.x < 4 * DD)
        xs[threadIdx.x / DD][threadIdx.x % DD] = x[blockIdx.x * 4 * DD + threadIdx.x];
    __syncthreads();
    for (int t = lane; t < TWO_D; t += 64) {
        float a0 = 0.f, a1 = 0.f;
#pragma unroll 8
        for (int k = 0; k < DD; ++k) {
            const float xv = xs[wave][k];
            a0 = fmaf(xv, W1[k * TWO_D + t], a0);
            a1 = fmaf(xv, W1[(DD + k) * TWO_D + t], a1);
        }
        Aout[row * TWO_D + t] = __float2half(a0 + b1[t]);
        Bout[row * TWO_D + t] = __float2half(a1);
    }
}

// hadd2+gelu+pack+3 MFMA for one ks step; always prefetch from NPTR_ (clamped)
#define STREAM_KS(PB_, ACC_, NPTR_, KS_)                                        \
  { const u32x4 aw = avp[KS_];                                                  \
    const u32x4 bw = PB_[KS_];                                                  \
    PB_[KS_] = *(const u32x4*)&(NPTR_)[(KS_) * 32 + q8];                        \
    const __half2 u0 = __hadd2(h2cast(aw.x), h2cast(bw.x));                     \
    const __half2 u1 = __hadd2(h2cast(aw.y), h2cast(bw.y));                     \
    const __half2 u2 = __hadd2(h2cast(aw.z), h2cast(bw.z));                     \
    const __half2 u3 = __hadd2(h2cast(aw.w), h2cast(bw.w));                     \
    f32x2 f0, f1, f2, f3;                                                       \
    { float2 t_ = __half22float2(u0); f0.x = t_.x; f0.y = t_.y; }               \
    { float2 t_ = __half22float2(u1); f1.x = t_.x; f1.y = t_.y; }               \
    { float2 t_ = __half22float2(u2); f2.x = t_.x; f2.y = t_.y; }               \
    { float2 t_ = __half22float2(u3); f3.x = t_.x; f3.y = t_.y; }               \
    const f32x2 g0 = gelu_poly2(f0);                                            \
    const f32x2 g1 = gelu_poly2(f1);                                            \
    const f32x2 g2 = gelu_poly2(f2);                                            \
    const f32x2 g3 = gelu_poly2(f3);                                            \
    union { f16x8 v; __half2 h2[4]; } hf;                                       \
    hf.h2[0] = __float22half2_rn(make_float2(g0.x, g0.y));                      \
    hf.h2[1] = __float22half2_rn(make_float2(g1.x, g1.y));                      \
    hf.h2[2] = __float22half2_rn(make_float2(g2.x, g2.y));                      \
    hf.h2[3] = __float22half2_rn(make_float2(g3.x, g3.y));                      \
    ACC_[0] = __builtin_amdgcn_mfma_f32_16x16x32_f16(bfrag[0][KS_], hf.v, ACC_[0], 0, 0, 0); \
    ACC_[1] = __builtin_amdgcn_mfma_f32_16x16x32_f16(bfrag[1][KS_], hf.v, ACC_[1], 0, 0, 0); \
    ACC_[2] = __builtin_amdgcn_mfma_f32_16x16x32_f16(bfrag[2][KS_], hf.v, ACC_[2], 0, 0, 0); \
  }

// consume pending epilogue state: ew from (ssp + 3 parallel swizzle partials),
// masked via jp (jp = HUGE for the dummy first iteration -> ew == 0 exactly)
#define EPI_CONSUME(L_, O_)                                                     \
  { const float full = (ssp + s1p) + (s2p + s3p);                               \
    const float ew = ((jp + n) <= rowi)                                         \
        ? __builtin_amdgcn_exp2f(sqrtf(full) * 1.44269504f) : 0.f;              \
    L_ += ew;                                                                   \
    f32x2 ew2; ew2 = ew;                                                        \
    _Pragma("unroll")                                                           \
    for (int t = 0; t < 3; ++t) {                                               \
      O_[t][0] = __builtin_elementwise_fma(ew2, pvp[t][0], O_[t][0]);           \
      O_[t][1] = __builtin_elementwise_fma(ew2, pvp[t][1], O_[t][1]);           \
    } }

// one row, single stream, PIPELINED epilogue: iteration k issues chunk-k's
// 3 independent quad-swizzles, consumes chunk-(k-1)'s under the next MFMA block.
#define PROCESS_ROW_PIPE(I_, ROW_, CSTART_, L_, O_)                             \
  { const int rowi = (I_);                                                      \
    u32x4 avp[3];                                                               \
    _Pragma("unroll")                                                           \
    for (int ks = 0; ks < 3; ++ks)                                              \
      avp[ks] = *(const u32x4*)&Arow[(size_t)(ROW_) * TWO_D + ks * 32 + q8];    \
    const int nch = (rowi + 16) >> 4;                                           \
    int c = (CSTART_);                                                          \
    if (c < nch) {                                                              \
      const __half* __restrict__ Bp = Bbase + (size_t)((c << 4) + n) * TWO_D;   \
      u32x4 pb[3];                                                              \
      _Pragma("unroll")                                                         \
      for (int ks = 0; ks < 3; ++ks) pb[ks] = *(const u32x4*)&Bp[ks * 32 + q8]; \
      f32x2 pvp[3][2];                                                          \
      _Pragma("unroll")                                                         \
      for (int t = 0; t < 3; ++t) { pvp[t][0] = 0.f; pvp[t][1] = 0.f; }         \
      float ssp = 0.f, s1p = 0.f, s2p = 0.f, s3p = 0.f;                         \
      int jp = 0x40000000;              /* dummy: masked -> ew = 0 */           \
      for (; c < nch; c += 4) {                                                 \
        const __half* __restrict__ Bn =                                         \
            ((c + 4) < nch) ? Bp + 64 * TWO_D : Bp;   /* clamped prefetch */    \
        f32x4 acc[3];                                                           \
        acc[0] = b2q[0]; acc[1] = b2q[1]; acc[2] = b2q[2];                      \
        _Pragma("unroll")                                                       \
        for (int ksi = 0; ksi < 3; ++ksi) { STREAM_KS(pb, acc, Bn, ksi); }      \
        /* EPI issue: local ss + 3 INDEPENDENT quad swizzles */                 \
        f32x2 ss2; ss2 = 0.f;                                                   \
        _Pragma("unroll")                                                       \
        for (int t = 0; t < 3; ++t) {                                           \
          f32x2 p01; p01.x = acc[t][0]; p01.y = acc[t][1];                      \
          f32x2 p23; p23.x = acc[t][2]; p23.y = acc[t][3];                      \
          ss2 = __builtin_elementwise_fma(p01, p01, ss2);                       \
          ss2 = __builtin_elementwise_fma(p23, p23, ss2);                       \
        }                                                                       \
        const float ss = ss2.x + ss2.y;                                         \
        const float s1 = __shfl_xor(ss, 16);                                    \
        const float s2 = __shfl_xor(ss, 32);                                    \
        const float s3 = __shfl_xor(ss, 48);                                    \
        /* consume previous chunk's epilogue (swizzle latency hidden) */        \
        EPI_CONSUME(L_, O_);                                                    \
        /* save pending */                                                      \
        _Pragma("unroll")                                                       \
        for (int t = 0; t < 3; ++t) {                                           \
          pvp[t][0].x = acc[t][0]; pvp[t][0].y = acc[t][1];                     \
          pvp[t][1].x = acc[t][2]; pvp[t][1].y = acc[t][3];                     \
        }                                                                       \
        ssp = ss; s1p = s1; s2p = s2; s3p = s3; jp = c << 4;                    \
        Bp = Bn;                                                                \
      }                                                                         \
      EPI_CONSUME(L_, O_);           /* drain the last pending chunk */         \
    } }

// reduce over n (16 lanes) and flush one row's partials to per-wave LDS slots
#define REDUCE_FLUSH(L_, O_, SEL_)                                              \
  { _Pragma("unroll")                                                           \
    for (int d = 1; d <= 8; d <<= 1) {                                          \
      L_ += __shfl_xor(L_, d);                                                  \
      _Pragma("unroll")                                                         \
      for (int t = 0; t < 3; ++t)                                               \
        _Pragma("unroll")                                                       \
        for (int r = 0; r < 2; ++r) {                                           \
          O_[t][r].x += __shfl_xor(O_[t][r].x, d);                              \
          O_[t][r].y += __shfl_xor(O_[t][r].y, d);                              \
        }                                                                       \
    }                                                                           \
    if (n == 0) {                                                               \
      _Pragma("unroll")                                                         \
      for (int t = 0; t < 3; ++t)                                               \
        _Pragma("unroll")                                                       \
        for (int r = 0; r < 2; ++r) {                                           \
          ored[wave][SEL_][t * 16 + 4 * q + 2 * r + 0] = O_[t][r].x;            \
          ored[wave][SEL_][t * 16 + 4 * q + 2 * r + 1] = O_[t][r].y;            \
        }                                                                       \
      if (q == 0) lred[wave][SEL_] = L_;                                        \
    } }

// Kernel 2: 1024 uniform pair-blocks x 4 waves (R16 champion skeleton), f16
// register-resident data path, single stream with pipelined epilogue.
__global__ __launch_bounds__(256) void pair_softmax_kernel(
        const __half* __restrict__ Arow,
        const __half* __restrict__ Brow,
        const __half* __restrict__ W2T,
        const float* __restrict__ b2,
        float* __restrict__ out) {
    const int batch = blockIdx.x >> 8;        // 0..3
    const int pr = blockIdx.x & 255;          // 0..255
    const int iH = (NN - 1) - pr;             // 256..511
    const int iL = pr;                        // 0..255
    const int cH = (iH >> 4) + 1;             // 17..32; cH + cL = 33
    const int rowH = batch * NN + iH;
    const int rowL = batch * NN + iL;
    const __half* __restrict__ Bbase = Brow + (size_t)batch * NN * TWO_D;

    const int tid = threadIdx.x;
    const int wave = tid >> 6;                // 0..3
    const int lane = tid & 63;
    const int n = lane & 15;   // j-local (C/D col); also W2T A-frag row f-local
    const int q = lane >> 4;   // quad
    const int q8 = q * 8;

    __shared__ float lred[4][2];
    __shared__ float ored[4][2][DD];

    // W2T fragments (A-operand) in registers
    f16x8 bfrag[3][3];
#pragma unroll
    for (int t = 0; t < 3; ++t)
#pragma unroll
        for (int ks = 0; ks < 3; ++ks)
            bfrag[t][ks] = *(const f16x8*)&W2T[(t * 16 + n) * TWO_D + ks * 32 + q8];
    // b2 quad folded into acc init
    f32x4 b2q[3];
#pragma unroll
    for (int t = 0; t < 3; ++t)
        b2q[t] = *(const f32x4*)&b2[t * 16 + 4 * q];

    // Light row's starting chunk: global idx = cH + c ≡ wave (mod 4)
    const int cstartL = (wave + 128 - cH) & 3;

    float lH = 0.f;
    f32x2 oH[3][2];
#pragma unroll
    for (int t = 0; t < 3; ++t)
#pragma unroll
        for (int r = 0; r < 2; ++r) oH[t][r] = 0.f;
    PROCESS_ROW_PIPE(iH, rowH, wave, lH, oH);
    REDUCE_FLUSH(lH, oH, 0);

    float lL = 0.f;
    f32x2 oL[3][2];
#pragma unroll
    for (int t = 0; t < 3; ++t)
#pragma unroll
        for (int r = 0; r < 2; ++r) oL[t][r] = 0.f;
    PROCESS_ROW_PIPE(iL, rowL, cstartL, lL, oL);
    REDUCE_FLUSH(lL, oL, 1);

    __syncthreads();
    if (tid < 2 * DD) {
        const int sel = tid / DD;
        const int f = tid - sel * DD;
        float L = 0.f, O = 0.f;
#pragma unroll
        for (int wv = 0; wv < 4; ++wv) {
            L += lred[wv][sel];
            O += ored[wv][sel][f];
        }
        const int row = sel ? rowL : rowH;
        out[row * DD + f] = O / L;
    }
}

extern "C" void kernel_launch(void* const* d_in, const int* in_sizes, int n_in,
                              void* d_out, int out_size, void* d_ws, size_t ws_size,
                              hipStream_t stream) {
    const float* x  = (const float*)d_in[0];
    const float* W1 = (const float*)d_in[1];
    const float* b1 = (const float*)d_in[2];
    const float* W2 = (const float*)d_in[3];
    const float* b2 = (const float*)d_in[4];
    float* outp = (float*)d_out;

    __half* A   = (__half*)d_ws;            // 2048*96 f16
    __half* Bb  = A + ROWS * TWO_D;         // 2048*96 f16
    __half* W2T = Bb + ROWS * TWO_D;        // 48*96 f16

    precompute_kernel<<<ROWS / 4 + 1, 256, 0, stream>>>(x, W1, b1, W2, A, Bb, W2T);
    pair_softmax_kernel<<<1024, 256, 0, stream>>>(A, Bb, W2T, b2, outp);
}

// Round 19
// 87.231 us; speedup vs baseline: 1.2078x; 1.0281x over previous
//
#include <hip/hip_runtime.h>
#include <hip/hip_bf16.h>
#include <hip/hip_fp16.h>
#include <math.h>

#define DD 48
#define NN 512
#define TWO_D 96
#define ROWS 2048   // B*N = 4*512

typedef __attribute__((ext_vector_type(8))) _Float16 f16x8;
typedef __attribute__((ext_vector_type(2))) _Float16 f16x2;
typedef __attribute__((ext_vector_type(4))) float f32x4;
typedef __attribute__((ext_vector_type(2))) float f32x2;
typedef __attribute__((ext_vector_type(4))) unsigned int u32x4;

__device__ __forceinline__ f16x2 h2cast(unsigned int u) { return __builtin_bit_cast(f16x2, u); }

// f16-NATIVE exact-erf GELU (deg-5 poly, R8-R17-verified shape) on ext-vector
// _Float16 (lowers to v_pk_*_f16; no HIP __half2 overload issues).
// Subnormal-safe: Horner in w = (uc/4)^2 (exact exponent shift) with
// coefficients rescaled by 16^i -> all O(1). h = u * (0.5 + uc*E(w)).
__device__ __forceinline__ f16x2 gelu_h2(f16x2 u) {
    f16x2 lim;  lim  = (_Float16)3.5777f;
    f16x2 nlim; nlim = (_Float16)(-3.5777f);
    const f16x2 uc = __builtin_elementwise_min(__builtin_elementwise_max(u, nlim), lim);
    f16x2 qtr; qtr = (_Float16)0.25f;
    const f16x2 uq = uc * qtr;          // exact (exponent shift)
    const f16x2 w  = uq * uq;           // = uc^2 / 16
    f16x2 c5; c5 = (_Float16)(-1.09522f);
    f16x2 c4; c4 = (_Float16)3.02716f;
    f16x2 c3; c3 = (_Float16)(-3.53192f);
    f16x2 c2; c2 = (_Float16)2.36067f;
    f16x2 c1; c1 = (_Float16)(-1.05336f);
    f16x2 c0; c0 = (_Float16)0.39886f;
    f16x2 E = __builtin_elementwise_fma(w, c5, c4);
    E = __builtin_elementwise_fma(w, E, c3);
    E = __builtin_elementwise_fma(w, E, c2);
    E = __builtin_elementwise_fma(w, E, c1);
    E = __builtin_elementwise_fma(w, E, c0);
    f16x2 hlf; hlf = (_Float16)0.5f;
    return u * __builtin_elementwise_fma(uc, E, hlf);
}

// Kernel 1: blocks 0..511: A[r][t] = f16(x_r @ W1[:48,t] + b1[t]);
//           Bb[r][t] = f16(x_r @ W1[48:,t]); block 512: W2T[f][k] = f16(W2[k][f])
__global__ __launch_bounds__(256) void precompute_kernel(
        const float* __restrict__ x,
        const float* __restrict__ W1,
        const float* __restrict__ b1,
        const float* __restrict__ W2,
        __half* __restrict__ Aout,
        __half* __restrict__ Bout,
        __half* __restrict__ W2T) {
    if (blockIdx.x == ROWS / 4) {
        for (int idx = threadIdx.x; idx < DD * TWO_D; idx += 256) {
            const int f = idx / TWO_D;
            const int k = idx - f * TWO_D;
            W2T[idx] = __float2half(W2[k * DD + f]);
        }
        return;
    }
    const int wave = threadIdx.x >> 6;
    const int lane = threadIdx.x & 63;
    const int row = blockIdx.x * 4 + wave;
    __shared__ float xs[4][DD];
    if (threadIdx.x < 4 * DD)
        xs[threadIdx.x / DD][threadIdx.x % DD] = x[blockIdx.x * 4 * DD + threadIdx.x];
    __syncthreads();
    for (int t = lane; t < TWO_D; t += 64) {
        float a0 = 0.f, a1 = 0.f;
#pragma unroll 8
        for (int k = 0; k < DD; ++k) {
            const float xv = xs[wave][k];
            a0 = fmaf(xv, W1[k * TWO_D + t], a0);
            a1 = fmaf(xv, W1[(DD + k) * TWO_D + t], a1);
        }
        Aout[row * TWO_D + t] = __float2half(a0 + b1[t]);
        Bout[row * TWO_D + t] = __float2half(a1);
    }
}

// pk_add + f16 gelu + 3 MFMA for one ks step; always prefetch from NPTR_ (clamped)
#define STREAM_KS(PB_, ACC_, NPTR_, KS_)                                        \
  { const u32x4 aw = avp[KS_];                                                  \
    const u32x4 bw = PB_[KS_];                                                  \
    PB_[KS_] = *(const u32x4*)&(NPTR_)[(KS_) * 32 + q8];                        \
    union { f16x8 v; f16x2 h2[4]; } hf;                                         \
    hf.h2[0] = gelu_h2(h2cast(aw.x) + h2cast(bw.x));                            \
    hf.h2[1] = gelu_h2(h2cast(aw.y) + h2cast(bw.y));                            \
    hf.h2[2] = gelu_h2(h2cast(aw.z) + h2cast(bw.z));                            \
    hf.h2[3] = gelu_h2(h2cast(aw.w) + h2cast(bw.w));                            \
    ACC_[0] = __builtin_amdgcn_mfma_f32_16x16x32_f16(bfrag[0][KS_], hf.v, ACC_[0], 0, 0, 0); \
    ACC_[1] = __builtin_amdgcn_mfma_f32_16x16x32_f16(bfrag[1][KS_], hf.v, ACC_[1], 0, 0, 0); \
    ACC_[2] = __builtin_amdgcn_mfma_f32_16x16x32_f16(bfrag[2][KS_], hf.v, ACC_[2], 0, 0, 0); \
  }

// consume pending epilogue state: ew from (ssp + 3 parallel swizzle partials),
// masked via jp (jp = HUGE for the dummy first iteration -> ew == 0 exactly)
#define EPI_CONSUME(L_, O_)                                                     \
  { const float full = (ssp + s1p) + (s2p + s3p);                               \
    const float ew = ((jp + n) <= rowi)                                         \
        ? __builtin_amdgcn_exp2f(sqrtf(full) * 1.44269504f) : 0.f;              \
    L_ += ew;                                                                   \
    f32x2 ew2; ew2 = ew;                                                        \
    _Pragma("unroll")                                                           \
    for (int t = 0; t < 3; ++t) {                                               \
      O_[t][0] = __builtin_elementwise_fma(ew2, pvp[t][0], O_[t][0]);           \
      O_[t][1] = __builtin_elementwise_fma(ew2, pvp[t][1], O_[t][1]);           \
    } }

// one row, single stream, PIPELINED epilogue: iteration k issues chunk-k's
// 3 independent quad-swizzles, consumes chunk-(k-1)'s under the next MFMA block.
#define PROCESS_ROW_PIPE(I_, ROW_, CSTART_, L_, O_)                             \
  { const int rowi = (I_);                                                      \
    u32x4 avp[3];                                                               \
    _Pragma("unroll")                                                           \
    for (int ks = 0; ks < 3; ++ks)                                              \
      avp[ks] = *(const u32x4*)&Arow[(size_t)(ROW_) * TWO_D + ks * 32 + q8];    \
    const int nch = (rowi + 16) >> 4;                                           \
    int c = (CSTART_);                                                          \
    if (c < nch) {                                                              \
      const __half* __restrict__ Bp = Bbase + (size_t)((c << 4) + n) * TWO_D;   \
      u32x4 pb[3];                                                              \
      _Pragma("unroll")                                                         \
      for (int ks = 0; ks < 3; ++ks) pb[ks] = *(const u32x4*)&Bp[ks * 32 + q8]; \
      f32x2 pvp[3][2];                                                          \
      _Pragma("unroll")                                                         \
      for (int t = 0; t < 3; ++t) { pvp[t][0] = 0.f; pvp[t][1] = 0.f; }         \
      float ssp = 0.f, s1p = 0.f, s2p = 0.f, s3p = 0.f;                         \
      int jp = 0x40000000;              /* dummy: masked -> ew = 0 */           \
      for (; c < nch; c += 4) {                                                 \
        const __half* __restrict__ Bn =                                         \
            ((c + 4) < nch) ? Bp + 64 * TWO_D : Bp;   /* clamped prefetch */    \
        f32x4 acc[3];                                                           \
        acc[0] = b2q[0]; acc[1] = b2q[1]; acc[2] = b2q[2];                      \
        _Pragma("unroll")                                                       \
        for (int ksi = 0; ksi < 3; ++ksi) { STREAM_KS(pb, acc, Bn, ksi); }      \
        /* EPI issue: local ss + 3 INDEPENDENT quad swizzles */                 \
        f32x2 ss2; ss2 = 0.f;                                                   \
        _Pragma("unroll")                                                       \
        for (int t = 0; t < 3; ++t) {                                           \
          f32x2 p01; p01.x = acc[t][0]; p01.y = acc[t][1];                      \
          f32x2 p23; p23.x = acc[t][2]; p23.y = acc[t][3];                      \
          ss2 = __builtin_elementwise_fma(p01, p01, ss2);                       \
          ss2 = __builtin_elementwise_fma(p23, p23, ss2);                       \
        }                                                                       \
        const float ss = ss2.x + ss2.y;                                         \
        const float s1 = __shfl_xor(ss, 16);                                    \
        const float s2 = __shfl_xor(ss, 32);                                    \
        const float s3 = __shfl_xor(ss, 48);                                    \
        /* consume previous chunk's epilogue (swizzle latency hidden) */        \
        EPI_CONSUME(L_, O_);                                                    \
        /* save pending */                                                      \
        _Pragma("unroll")                                                       \
        for (int t = 0; t < 3; ++t) {                                           \
          pvp[t][0].x = acc[t][0]; pvp[t][0].y = acc[t][1];                     \
          pvp[t][1].x = acc[t][2]; pvp[t][1].y = acc[t][3];                     \
        }                                                                       \
        ssp = ss; s1p = s1; s2p = s2; s3p = s3; jp = c << 4;                    \
        Bp = Bn;                                                                \
      }                                                                         \
      EPI_CONSUME(L_, O_);           /* drain the last pending chunk */         \
    } }

// reduce over n (16 lanes) and flush one row's partials to per-wave LDS slots
#define REDUCE_FLUSH(L_, O_, SEL_)                                              \
  { _Pragma("unroll")                                                           \
    for (int d = 1; d <= 8; d <<= 1) {                                          \
      L_ += __shfl_xor(L_, d);                                                  \
      _Pragma("unroll")                                                         \
      for (int t = 0; t < 3; ++t)                                               \
        _Pragma("unroll")                                                       \
        for (int r = 0; r < 2; ++r) {                                           \
          O_[t][r].x += __shfl_xor(O_[t][r].x, d);                              \
          O_[t][r].y += __shfl_xor(O_[t][r].y, d);                              \
        }                                                                       \
    }                                                                           \
    if (n == 0) {                                                               \
      _Pragma("unroll")                                                         \
      for (int t = 0; t < 3; ++t)                                               \
        _Pragma("unroll")                                                       \
        for (int r = 0; r < 2; ++r) {                                           \
          ored[wave][SEL_][t * 16 + 4 * q + 2 * r + 0] = O_[t][r].x;            \
          ored[wave][SEL_][t * 16 + 4 * q + 2 * r + 1] = O_[t][r].y;            \
        }                                                                       \
      if (q == 0) lred[wave][SEL_] = L_;                                        \
    } }

// Kernel 2: 1024 uniform pair-blocks x 4 waves (R17 champion skeleton), f16
// register-resident data path, single stream with pipelined epilogue, f16-native
// gelu (no cvt/pack plumbing in the hot loop).
__global__ __launch_bounds__(256) void pair_softmax_kernel(
        const __half* __restrict__ Arow,
        const __half* __restrict__ Brow,
        const __half* __restrict__ W2T,
        const float* __restrict__ b2,
        float* __restrict__ out) {
    const int batch = blockIdx.x >> 8;        // 0..3
    const int pr = blockIdx.x & 255;          // 0..255
    const int iH = (NN - 1) - pr;             // 256..511
    const int iL = pr;                        // 0..255
    const int cH = (iH >> 4) + 1;             // 17..32; cH + cL = 33
    const int rowH = batch * NN + iH;
    const int rowL = batch * NN + iL;
    const __half* __restrict__ Bbase = Brow + (size_t)batch * NN * TWO_D;

    const int tid = threadIdx.x;
    const int wave = tid >> 6;                // 0..3
    const int lane = tid & 63;
    const int n = lane & 15;   // j-local (C/D col); also W2T A-frag row f-local
    const int q = lane >> 4;   // quad
    const int q8 = q * 8;

    __shared__ float lred[4][2];
    __shared__ float ored[4][2][DD];

    // W2T fragments (A-operand) in registers
    f16x8 bfrag[3][3];
#pragma unroll
    for (int t = 0; t < 3; ++t)
#pragma unroll
        for (int ks = 0; ks < 3; ++ks)
            bfrag[t][ks] = *(const f16x8*)&W2T[(t * 16 + n) * TWO_D + ks * 32 + q8];
    // b2 quad folded into acc init
    f32x4 b2q[3];
#pragma unroll
    for (int t = 0; t < 3; ++t)
        b2q[t] = *(const f32x4*)&b2[t * 16 + 4 * q];

    // Light row's starting chunk: global idx = cH + c ≡ wave (mod 4)
    const int cstartL = (wave + 128 - cH) & 3;

    float lH = 0.f;
    f32x2 oH[3][2];
#pragma unroll
    for (int t = 0; t < 3; ++t)
#pragma unroll
        for (int r = 0; r < 2; ++r) oH[t][r] = 0.f;
    PROCESS_ROW_PIPE(iH, rowH, wave, lH, oH);
    REDUCE_FLUSH(lH, oH, 0);

    float lL = 0.f;
    f32x2 oL[3][2];
#pragma unroll
    for (int t = 0; t < 3; ++t)
#pragma unroll
        for (int r = 0; r < 2; ++r) oL[t][r] = 0.f;
    PROCESS_ROW_PIPE(iL, rowL, cstartL, lL, oL);
    REDUCE_FLUSH(lL, oL, 1);

    __syncthreads();
    if (tid < 2 * DD) {
        const int sel = tid / DD;
        const int f = tid - sel * DD;
        float L = 0.f, O = 0.f;
#pragma unroll
        for (int wv = 0; wv < 4; ++wv) {
            L += lred[wv][sel];
            O += ored[wv][sel][f];
        }
        const int row = sel ? rowL : rowH;
        out[row * DD + f] = O / L;
    }
}

extern "C" void kernel_launch(void* const* d_in, const int* in_sizes, int n_in,
                              void* d_out, int out_size, void* d_ws, size_t ws_size,
                              hipStream_t stream) {
    const float* x  = (const float*)d_in[0];
    const float* W1 = (const float*)d_in[1];
    const float* b1 = (const float*)d_in[2];
    const float* W2 = (const float*)d_in[3];
    const float* b2 = (const float*)d_in[4];
    float* outp = (float*)d_out;

    __half* A   = (__half*)d_ws;            // 2048*96 f16
    __half* Bb  = A + ROWS * TWO_D;         // 2048*96 f16
    __half* W2T = Bb + ROWS * TWO_D;        // 48*96 f16

    precompute_kernel<<<ROWS / 4 + 1, 256, 0, stream>>>(x, W1, b1, W2, A, Bb, W2T);
    pair_softmax_kernel<<<1024, 256, 0, stream>>>(A, Bb, W2T, b2, outp);
}